// Round 2
// baseline (69.350 us; speedup 1.0000x reference)
//
#include <hip/hip_runtime.h>

// MaxMinComp: out[b,o] = max_i min(x[b,i], W[i,o]); B=1024, IN=OUT=512, fp32.
// fp16 packed-u16 tropical GEMM (values in [0,1) => IEEE order == u16 order).
//
// R6 post-mortem: -33% LDS-read instrs was NEUTRAL -> kernel is not LDS-read
// bound; the ~8us residual (of ~14us) is barrier lockstep with 1 block/CU
// (16 waves all drain at the same 6 barriers, nothing else resident).
// R7: 2 blocks/CU. 512-thr blocks (8 waves), tile 16x64, grid (64,8)=512.
//  - quarter-wave k-slices (32), same 8x8 lane tile -> identical inner loop,
//    same 32 pk-instr per ds_read_b128 (VALU floor 3.4us preserved).
//  - padded LDS strides replace XOR swizzle: x stride 80B (quarters -> distinct
//    bank octets, conflict-free), w stride 144B (2-way = free). Staging writes
//    re-derived <=2-way.
//  - fold 32->8 partials: shfl_xor(16) + permlane32_swap; overlay 16KB.
//  - LDS 47104B/block -> 94KB/CU @ 2 blocks; launch_bounds(512,4) -> 2/CU.

typedef unsigned int u32;
typedef u32 u32x4 __attribute__((ext_vector_type(4)));
typedef float f4 __attribute__((ext_vector_type(4)));
typedef float f2 __attribute__((ext_vector_type(2)));
typedef __fp16 h2 __attribute__((ext_vector_type(2)));

#define XSTRIDE 80                 // bytes per kp row: 16 rows * 4B + 16B pad
#define WSTRIDE 144                // bytes per k row: 32 colpairs * 4B + 16B pad
#define XB2 (64 * XSTRIDE)         // 5120
#define WB2 (128 * WSTRIDE)        // 18432
#define BUFB2 (XB2 + WB2)          // 23552; double buffer = 47104

static __device__ __forceinline__ u32 pkcvt(float a, float b) {
  return __builtin_bit_cast(u32, __builtin_amdgcn_cvt_pkrtz(a, b));
}
static __device__ __forceinline__ u32 pkmax(u32 a, u32 b) {
  u32 d; asm("v_pk_max_u16 %0, %1, %2" : "=v"(d) : "v"(a), "v"(b)); return d;
}
// min(broadcast(x.lo), w) : out.lo=min(x.lo,w.lo), out.hi=min(x.lo,w.hi)
static __device__ __forceinline__ u32 pkmin_bl(u32 x, u32 w) {
  u32 d;
  asm("v_pk_min_u16 %0, %1, %2 op_sel:[0,0] op_sel_hi:[0,1]"
      : "=v"(d) : "v"(x), "v"(w));
  return d;
}
// min(broadcast(x.hi), w)
static __device__ __forceinline__ u32 pkmin_bh(u32 x, u32 w) {
  u32 d;
  asm("v_pk_min_u16 %0, %1, %2 op_sel:[1,0] op_sel_hi:[1,1]"
      : "=v"(d) : "v"(x), "v"(w));
  return d;
}
// max(v[lane], v[lane^32]) in every lane.
static __device__ __forceinline__ u32 halfswap_max(u32 v) {
  u32 a = v, b = v;
  asm("v_permlane32_swap_b32 %0, %1" : "+v"(a), "+v"(b));
  return pkmax(a, b);
}

__global__ __launch_bounds__(512, 4) void maxmin_v7(const float* __restrict__ X,
                                                    const float* __restrict__ W,
                                                    float* __restrict__ Out) {
  __shared__ __align__(16) char smem[2 * BUFB2];  // 47104B

  const int tid  = threadIdx.x;
  const int wv   = tid >> 6;        // wave 0..7
  const int lane = tid & 63;
  const int qw   = lane >> 4;       // quarter-wave = k-slice sub-index 0..3
  const int ty   = (lane >> 3) & 1; // rows 8*ty .. 8*ty+7
  const int tx   = lane & 7;        // cols 8*tx .. 8*tx+7 (colpairs 4tx..4tx+3)
  const int b0   = blockIdx.x * 16;
  const int o0   = blockIdx.y * 64;

  // x staging: row = tid&15, f4 k-group = tid>>4 (k = 4*xq4 .. +3)
  const int xr  = tid & 15;
  const int xq4 = tid >> 4;         // 0..31
  const float* xg = X + (b0 + xr) * 512 + 4 * xq4;
  const int xw0 = (2 * xq4) * XSTRIDE + 4 * xr;   // pair kp=2*xq4 (+1 at +XSTRIDE)

  // w staging: k-row = tid>>2 (0..127), 16-col group = tid&3
  const int wkk = tid >> 2;
  const int wc  = tid & 3;
  const float* wg = W + wkk * 512 + o0 + 16 * wc;
  const int ww0 = XB2 + wkk * WSTRIDE + 32 * wc;  // colpairs 8wc..8wc+7

  // compute-side: slice s = 4*wv + qw owns kpairs {2s, 2s+1} per chunk
  const int kpb = 8 * wv + 2 * qw;

  u32 acc[8][4] = {};  // [row j][colpair cc], packed (col even, col odd)

  auto stage = [&](char* buf, f4 xv, f4 w0, f4 w1, f4 w2, f4 w3) {
    *(u32*)(buf + xw0)           = pkcvt(xv.x, xv.y);
    *(u32*)(buf + xw0 + XSTRIDE) = pkcvt(xv.z, xv.w);
    u32x4 pa = {pkcvt(w0.x, w0.y), pkcvt(w0.z, w0.w),
                pkcvt(w1.x, w1.y), pkcvt(w1.z, w1.w)};
    u32x4 pb = {pkcvt(w2.x, w2.y), pkcvt(w2.z, w2.w),
                pkcvt(w3.x, w3.y), pkcvt(w3.z, w3.w)};
    *(u32x4*)(buf + ww0)      = pa;   // colpairs 8wc..8wc+3
    *(u32x4*)(buf + ww0 + 16) = pb;   // colpairs 8wc+4..8wc+7
  };

  // prologue: stage chunk 0
  {
    f4 xv = *(const f4*)xg;
    const f4* wp = (const f4*)wg;
    stage(smem, xv, wp[0], wp[1], wp[2], wp[3]);
  }
  __syncthreads();

  for (int c = 0; c < 4; ++c) {
    f4 nx = {}, n0 = {}, n1 = {}, n2 = {}, n3 = {};
    if (c < 3) {  // prefetch next chunk before compute
      nx = *(const f4*)(xg + (c + 1) * 128);
      const f4* wp = (const f4*)(wg + (c + 1) * 128 * 512);
      n0 = wp[0]; n1 = wp[1]; n2 = wp[2]; n3 = wp[3];
    }
    const char* buf = smem + (c & 1) * BUFB2;
#pragma unroll
    for (int q = 0; q < 2; ++q) {
      const int kp = kpb + q;
      u32x4 x0 = *(const u32x4*)(buf + kp * XSTRIDE + 32 * ty);       // rows 8ty..+3
      u32x4 x1 = *(const u32x4*)(buf + kp * XSTRIDE + 32 * ty + 16);  // rows 8ty+4..+7
      u32x4 wl = *(const u32x4*)(buf + XB2 + (2 * kp) * WSTRIDE + 16 * tx);           // k even
      u32x4 wh = *(const u32x4*)(buf + XB2 + (2 * kp) * WSTRIDE + WSTRIDE + 16 * tx); // k odd
#pragma unroll
      for (int j = 0; j < 4; ++j)
#pragma unroll
        for (int cc = 0; cc < 4; ++cc) {
          acc[j][cc]     = pkmax(acc[j][cc],     pkmin_bl(x0[j], wl[cc]));
          acc[j][cc]     = pkmax(acc[j][cc],     pkmin_bh(x0[j], wh[cc]));
          acc[4 + j][cc] = pkmax(acc[4 + j][cc], pkmin_bl(x1[j], wl[cc]));
          acc[4 + j][cc] = pkmax(acc[4 + j][cc], pkmin_bh(x1[j], wh[cc]));
        }
    }
    if (c < 3) stage(smem + ((c + 1) & 1) * BUFB2, nx, n0, n1, n2, n3);
    __syncthreads();
  }

  // fold 4 quarter-wave k-slices in-register: lane^16, then lane^32
#pragma unroll
  for (int j = 0; j < 8; ++j)
#pragma unroll
    for (int cc = 0; cc < 4; ++cc) {
      u32 v = acc[j][cc];
      v = pkmax(v, (u32)__shfl_xor((int)v, 16, 64));
      acc[j][cc] = halfswap_max(v);
    }

  // epilogue: 8 wave-partials -> 16KB overlay [wv][row 0..15][colpair 0..31]
  if (qw == 0) {
#pragma unroll
    for (int j = 0; j < 8; ++j) {
      u32x4 v = {acc[j][0], acc[j][1], acc[j][2], acc[j][3]};
      *(u32x4*)(smem + wv * 2048 + (8 * ty + j) * 128 + tx * 16) = v;
    }
  }
  __syncthreads();

  const int row = tid >> 5;  // 0..15
  const int cp  = tid & 31;  // col-pair
  const int cb  = row * 128 + cp * 4;
  u32 m = *(const u32*)(smem + cb);
#pragma unroll
  for (int g = 1; g < 8; ++g) m = pkmax(m, *(const u32*)(smem + g * 2048 + cb));
  h2 hm = __builtin_bit_cast(h2, m);
  f2 o = {(float)hm.x, (float)hm.y};
  *(f2*)(Out + (b0 + row) * 512 + o0 + cp * 2) = o;
}

extern "C" void kernel_launch(void* const* d_in, const int* in_sizes, int n_in,
                              void* d_out, int out_size, void* d_ws, size_t ws_size,
                              hipStream_t stream) {
  const float* x = (const float*)d_in[0];
  const float* w = (const float*)d_in[1];
  float* out = (float*)d_out;
  (void)in_sizes; (void)n_in; (void)out_size; (void)d_ws; (void)ws_size;
  dim3 grid(1024 / 16, 512 / 64);  // 512 blocks = 2/CU, 8 waves each
  maxmin_v7<<<grid, 512, 0, stream>>>(x, w, out);
}

// Round 3
// 67.398 us; speedup vs baseline: 1.0290x; 1.0290x over previous
//
#include <hip/hip_runtime.h>

// MaxMinComp: out[b,o] = max_i min(x[b,i], W[i,o]); B=1024, IN=OUT=512, fp32.
// fp16 packed-u16 tropical GEMM (values in [0,1) => IEEE order == u16 order).
//
// R6 (-33% LDS instr) and R7 (2 blocks/CU) were both NEUTRAL -> kernel is not
// LDS-bound and not fixable by block overlap. Residual ~8us (of ~14us) charged
// to the 4-chunk pipeline: per-chunk vmcnt drain + staging + barrier, 6-7
// full-block drains at 1 block/CU.
// R8: single mega-stage. Whole problem fits LDS at fp16: x 32x512 (32KB,
// XOR-swizzled) + w 512x64 (64KB) = 96KB. Issue all 12 f4 global loads up
// front (one latency hit), convert+write once, ONE barrier, then the whole
// compute loop runs with zero barriers/waitcnts. 3 barriers total (was 6-7).
// Inner loop / layouts / fold / epilogue identical to R6 (verified).

typedef unsigned int u32;
typedef u32 u32x2 __attribute__((ext_vector_type(2)));
typedef u32 u32x4 __attribute__((ext_vector_type(4)));
typedef float f4 __attribute__((ext_vector_type(4)));
typedef float f2 __attribute__((ext_vector_type(2)));
typedef __fp16 h2 __attribute__((ext_vector_type(2)));

#define XB 8192               // x pairs per chunk: 64 kp * 32 rows * 4B
#define WB 16384              // w pairs per chunk: 128 k * 32 colpairs * 4B
#define BUFB (XB + WB)        // 24576 per chunk; 4 chunks = 98304B resident

static __device__ __forceinline__ u32 pkcvt(float a, float b) {
  return __builtin_bit_cast(u32, __builtin_amdgcn_cvt_pkrtz(a, b));
}
static __device__ __forceinline__ u32 pkmax(u32 a, u32 b) {
  u32 d; asm("v_pk_max_u16 %0, %1, %2" : "=v"(d) : "v"(a), "v"(b)); return d;
}
// min(broadcast(x.lo), w) : out.lo=min(x.lo,w.lo), out.hi=min(x.lo,w.hi)
static __device__ __forceinline__ u32 pkmin_bl(u32 x, u32 w) {
  u32 d;
  asm("v_pk_min_u16 %0, %1, %2 op_sel:[0,0] op_sel_hi:[0,1]"
      : "=v"(d) : "v"(x), "v"(w));
  return d;
}
// min(broadcast(x.hi), w)
static __device__ __forceinline__ u32 pkmin_bh(u32 x, u32 w) {
  u32 d;
  asm("v_pk_min_u16 %0, %1, %2 op_sel:[1,0] op_sel_hi:[1,1]"
      : "=v"(d) : "v"(x), "v"(w));
  return d;
}
// max(v[lane], v[lane^32]) in every lane.
static __device__ __forceinline__ u32 halfswap_max(u32 v) {
  u32 a = v, b = v;
  asm("v_permlane32_swap_b32 %0, %1" : "+v"(a), "+v"(b));
  return pkmax(a, b);
}

__global__ __launch_bounds__(1024, 4) void maxmin_v8(const float* __restrict__ X,
                                                     const float* __restrict__ W,
                                                     float* __restrict__ Out) {
  __shared__ __align__(16) char smem[4 * BUFB];  // 96KB staging; 64KB overlay

  const int tid  = threadIdx.x;
  const int wv   = tid >> 6;   // wave 0..15
  const int lane = tid & 63;
  const int sh   = lane >> 5;  // half-wave = k-slice parity
  const int l5   = lane & 31;
  const int ty   = l5 >> 3;    // rows 8*ty .. 8*ty+7
  const int tx   = l5 & 7;     // cols 8*tx .. 8*tx+7 (colpairs 4*tx..4*tx+3)
  const int b0   = blockIdx.x * 32;
  const int o0   = blockIdx.y * 64;

  // x staging: r = tid>>5, kq = tid&31 -> coalesced 512B rows.
  const int xr  = tid >> 5;
  const int xkq = tid & 31;
  const float* xg = X + (b0 + xr) * 512 + xkq * 4;
  // LDS x write: pair kp=2kq (+1), addr = kp*128 + 4*(r ^ (kp&28)); the +1 pair
  // has the same xor -> second store at +128 (merges to ds_write2_b32).
  const int xw0 = (2 * xkq) * 128 + 4 * (xr ^ ((2 * xkq) & 28));

  // w staging: rows kk=tid>>4 (0..63) and kk+64; 4 cols per thread per row.
  const int wkk = tid >> 4;
  const int wc4 = tid & 15;
  const float* wg = W + wkk * 512 + o0 + wc4 * 4;
  const int ww0 = XB + wkk * 128 + wc4 * 8;

  // compute-side: slice = half-wave; per chunk this slice owns kpairs
  // kpb, kpb+1 (4 k). 32 slices x 2 kpairs = 64 kpairs/chunk.
  const int kpb = 4 * wv + 2 * sh;
  const int wro = XB + 16 * tx;

  u32 acc[8][4] = {};  // [row j][colpair cc], packed (col even, col odd)

  // ---- mega-stage: load ALL chunks, then convert+write ALL chunks ----
  {
    f4 xv[4], wa[4], wb[4];
#pragma unroll
    for (int c = 0; c < 4; ++c) {
      xv[c] = *(const f4*)(xg + c * 128);
      wa[c] = *(const f4*)(wg + c * 128 * 512);
      wb[c] = *(const f4*)(wg + c * 128 * 512 + 64 * 512);
    }
#pragma unroll
    for (int c = 0; c < 4; ++c) {
      char* buf = smem + c * BUFB;
      *(u32*)(buf + xw0)       = pkcvt(xv[c].x, xv[c].y);
      *(u32*)(buf + xw0 + 128) = pkcvt(xv[c].z, xv[c].w);
      u32x2 wpa = {pkcvt(wa[c].x, wa[c].y), pkcvt(wa[c].z, wa[c].w)};
      *(u32x2*)(buf + ww0) = wpa;
      u32x2 wpb = {pkcvt(wb[c].x, wb[c].y), pkcvt(wb[c].z, wb[c].w)};
      *(u32x2*)(buf + ww0 + 64 * 128) = wpb;
    }
  }
  __syncthreads();

  // ---- compute: 8 kp per slice, no barriers, no waitcnt drains ----
#pragma unroll
  for (int c = 0; c < 4; ++c) {
    const char* buf = smem + c * BUFB;
#pragma unroll
    for (int q = 0; q < 2; ++q) {
      const int kp = kpb + q;     // this half-wave's k-pair
      const int m  = kp & 28;     // same for both halves (kpb differs by 2)
      u32x4 x0 = *(const u32x4*)(buf + kp * 128 + 4 * ((8 * ty) ^ m));      // rows 8ty..+3
      u32x4 x1 = *(const u32x4*)(buf + kp * 128 + 4 * ((8 * ty + 4) ^ m));  // rows 8ty+4..+7
      u32x4 wl = *(const u32x4*)(buf + wro + (2 * kp) * 128);        // k even, 8 cols
      u32x4 wh = *(const u32x4*)(buf + wro + (2 * kp) * 128 + 128);  // k odd,  8 cols
#pragma unroll
      for (int j = 0; j < 4; ++j)
#pragma unroll
        for (int cc = 0; cc < 4; ++cc) {
          acc[j][cc]     = pkmax(acc[j][cc],     pkmin_bl(x0[j], wl[cc]));
          acc[j][cc]     = pkmax(acc[j][cc],     pkmin_bh(x0[j], wh[cc]));
          acc[4 + j][cc] = pkmax(acc[4 + j][cc], pkmin_bl(x1[j], wl[cc]));
          acc[4 + j][cc] = pkmax(acc[4 + j][cc], pkmin_bh(x1[j], wh[cc]));
        }
    }
  }

  // fold the two half-wave k-slices in-register (VALU pipe): 32 -> 16 partials
#pragma unroll
  for (int j = 0; j < 8; ++j)
#pragma unroll
    for (int cc = 0; cc < 4; ++cc) acc[j][cc] = halfswap_max(acc[j][cc]);

  __syncthreads();  // staging reads done; overlay may overwrite

  // epilogue: 16 wave-partials -> 64KB overlay [wv][row 0..31][colpair 0..31]
  if (sh == 0) {
#pragma unroll
    for (int j = 0; j < 8; ++j) {
      u32x4 v = {acc[j][0], acc[j][1], acc[j][2], acc[j][3]};
      *(u32x4*)(smem + wv * 4096 + (8 * ty + j) * 128 + tx * 16) = v;
    }
  }
  __syncthreads();

  const int row = tid >> 5;  // 0..31
  const int cp  = tid & 31;  // col-pair
  const int cb  = row * 128 + cp * 4;
  u32 m = *(const u32*)(smem + cb);
#pragma unroll
  for (int g = 1; g < 16; ++g) m = pkmax(m, *(const u32*)(smem + g * 4096 + cb));
  h2 hm = __builtin_bit_cast(h2, m);
  f2 o = {(float)hm.x, (float)hm.y};
  *(f2*)(Out + (b0 + row) * 512 + o0 + cp * 2) = o;
}

extern "C" void kernel_launch(void* const* d_in, const int* in_sizes, int n_in,
                              void* d_out, int out_size, void* d_ws, size_t ws_size,
                              hipStream_t stream) {
  const float* x = (const float*)d_in[0];
  const float* w = (const float*)d_in[1];
  float* out = (float*)d_out;
  (void)in_sizes; (void)n_in; (void)out_size; (void)d_ws; (void)ws_size;
  dim3 grid(1024 / 32, 512 / 64);  // 256 blocks = 1/CU, 16 waves each
  maxmin_v8<<<grid, 1024, 0, stream>>>(x, w, out);
}